// Round 6
// baseline (589.881 us; speedup 1.0000x reference)
//
#include <hip/hip_runtime.h>
#include <math.h>

#define N16 1600
#define M 32
#define XSZ 51200
#define BIS_IT 28
#define EPSF 1e-12f

// Cross-phase communication relies on kernel-boundary coherence (sequential
// launches, release/acquire at dispatch boundaries). No device-scope
// atomics/stores anywhere (round-0 evidence: agent-scope ops caused 479 MB
// WRITE_SIZE/solve for a 13.5 MB payload = 35x write-through amplification).

// ---------------- phase: resize (168 blocks) --------------------------------
__device__ void taps1d(int o, int* lo, int* hi, float* wsum, float w[8]) {
  int l = 4 * o - 2, h = 4 * o + 5;
  if (l < 0) l = 0;
  if (h > 159) h = 159;
  float c = 4.f * o + 1.5f, s = 0.f;
  for (int x = l; x <= h; ++x) {
    float ww = 1.f - fabsf((float)x - c) * 0.25f;
    w[x - l] = ww;
    s += ww;
  }
  *lo = l; *hi = h; *wsum = s;
}

__global__ void __launch_bounds__(256)
k_resize(const float* __restrict__ in, float* __restrict__ rz) {
  const int bx = blockIdx.x, t = threadIdx.x;
  int map = bx / 7;
  int o = (bx % 7) * 256 + t;
  if (o >= N16) return;
  int oy = o / 40, ox = o % 40;
  int ly, hy, lx, hx; float sy, sx; float wy[8], wx[8];
  taps1d(oy, &ly, &hy, &sy, wy);
  taps1d(ox, &lx, &hx, &sx, wx);
  const float* src = in + (size_t)map * 160 * 160;
  float acc = 0.f;
  for (int y = ly; y <= hy; ++y) {
    float a = 0.f;
    const float* row = src + y * 160;
    for (int x = lx; x <= hx; ++x) a += wx[x - lx] * row[x];
    acc += wy[y - ly] * a;
  }
  rz[map * N16 + o] = acc / (sy * sx);
}

// ---------------- phase: prep (23 blocks) -----------------------------------
__global__ void __launch_bounds__(256)
k_prep(const float* __restrict__ rz, float* __restrict__ F,
       int* __restrict__ flags) {
  __shared__ int sp[256];
  __shared__ int sn[256];
  const int bx = blockIdx.x, t = threadIdx.x;
  if (bx < 16) {
    int b = bx >> 1, c = bx & 1;
    const float* m = rz + (b * 3 + c) * N16;
    int cp = 0, cn = 0;
    for (int o = t; o < N16; o += 256) {
      float v = m[o];
      cp += (v > 0.f);
      cn += (v < 0.f);
    }
    sp[t] = cp; sn[t] = cn;
    __syncthreads();
    for (int s = 128; s > 0; s >>= 1) {
      if (t < s) { sp[t] += sp[t + s]; sn[t] += sn[t + s]; }
      __syncthreads();
    }
    if (t == 0) flags[bx] = (sp[0] == 0 || sn[0] == 0) ? 1 : 0;
  } else {
    int n = (bx - 16) * 256 + t;
    if (n < N16) {
      float x = rz[n], y = rz[N16 + n], z = rz[2 * N16 + n];
      float nrm = sqrtf(x * x + y * y + z * z);
      float s = 1.f / fmaxf(nrm, EPSF);
      F[n * 3 + 0] = x * s;
      F[n * 3 + 1] = y * s;
      F[n * 3 + 2] = z * s;
    }
  }
}

// ---------------- phase: degree + G4 + X0 init (100 blocks) -----------------
__global__ void __launch_bounds__(256)
k_degree(const float* __restrict__ F, float* __restrict__ R,
         float* __restrict__ G4f, float* __restrict__ X0) {
  __shared__ float Fl[4800];
  __shared__ float red[256];
  const int bx = blockIdx.x, t = threadIdx.x;
  for (int s = t; s < 4800; s += 256) Fl[s] = F[s];
  __syncthreads();
  int rl = t >> 4, jt = t & 15;
  int i = bx * 16 + rl;
  float fx = Fl[i * 3], fy = Fl[i * 3 + 1], fz = Fl[i * 3 + 2];
  float s = 0.f;
#pragma unroll 8
  for (int j = jt; j < N16; j += 16) {
    float w = fx * Fl[j * 3] + fy * Fl[j * 3 + 1] + fz * Fl[j * 3 + 2];
    if (w > 0.f) s += w;
  }
  red[t] = s;
  __syncthreads();
  for (int st = 8; st > 0; st >>= 1) {
    if (jt < st) red[t] += red[t + st];
    __syncthreads();
  }
  if (jt == 0) {
    float d = red[t];
    if (d < EPSF) d = 1.f;
    float r = rsqrtf(d);
    R[i] = r;
    G4f[i * 4 + 0] = r * fx;
    G4f[i * 4 + 1] = r * fy;
    G4f[i * 4 + 2] = r * fz;
    G4f[i * 4 + 3] = 0.f;
  }
  for (int e = t; e < 512; e += 256) {
    int n = bx * 16 + (e >> 5);
    int k = e & 31;
    unsigned u = ((unsigned)n * 2654435761u) ^ ((unsigned)k * 0x9E3779B9u);
    u = u * 1664525u + 1013904223u;
    u ^= u >> 16; u *= 2246822519u; u ^= u >> 13;
    X0[n * M + k] = ((float)(u >> 8) * (1.f / 8388608.f)) - 1.f;
  }
}

// ---------------- phase: MV (200 blocks = 100 i-groups x 2 k-halves) --------
// Block owns 16 i-rows x 16 k-cols, sums FULL j (25 chunks of 64): one plain
// store per output, no atomics. Ws (16x64 w values) staged once per chunk and
// reused by all 16 k. Register-staged double buffer (issue-early/write-late).
__global__ void __launch_bounds__(256)
k_mv(const float* __restrict__ F, const float4* __restrict__ G4,
     const float* __restrict__ R, const float* __restrict__ Xin,
     float* __restrict__ Xout) {
  __shared__ float Ws[2][1088];    // [16 i][68] per buffer
  __shared__ float XsT[2][1088];   // [16 k][68] per buffer (transposed X)
  __shared__ float Red[16 * 264];  // 16 jg pages, padded
  const int bx = blockIdx.x, t = threadIdx.x;
  const int ig = bx >> 1, kh = bx & 1;
  const int i0 = ig * 16, kbase = kh * 16;
  const int rg = t & 3, kg = (t >> 2) & 3, jg = t >> 4;  // compute: 4x4x16
  const int sj = t >> 2, sq = t & 3;                     // X stage: 64 j x 4 q
  const int wil = t & 15, wjg = t >> 4;                  // W stage: 16 i x 16 j
  const float fx = F[(i0 + wil) * 3 + 0];
  const float fy = F[(i0 + wil) * 3 + 1];
  const float fz = F[(i0 + wil) * 3 + 2];

  float acc[4][4];
#pragma unroll
  for (int r = 0; r < 4; ++r)
#pragma unroll
    for (int kk = 0; kk < 4; ++kk) acc[r][kk] = 0.f;

  // prologue: stage chunk 0 into buffer 0
  {
    float4 xs = ((const float4*)Xin)[(size_t)sj * 8 + kh * 4 + sq];
    XsT[0][(sq * 4 + 0) * 68 + sj] = xs.x;
    XsT[0][(sq * 4 + 1) * 68 + sj] = xs.y;
    XsT[0][(sq * 4 + 2) * 68 + sj] = xs.z;
    XsT[0][(sq * 4 + 3) * 68 + sj] = xs.w;
#pragma unroll
    for (int q = 0; q < 4; ++q) {
      float4 g = G4[wjg + 16 * q];
      Ws[0][wil * 68 + wjg + 16 * q] =
          fmaxf(fx * g.x + fy * g.y + fz * g.z, 0.f);
    }
  }
  __syncthreads();

  for (int c = 0; c < 25; ++c) {
    const int cur = c & 1, nxt = cur ^ 1;
    float4 xs = {0.f, 0.f, 0.f, 0.f};
    float4 ga[4];
    if (c < 24) {  // issue next-chunk loads early (latency hides under compute)
      const int jb = (c + 1) * 64;
      xs = ((const float4*)Xin)[(size_t)(jb + sj) * 8 + kh * 4 + sq];
#pragma unroll
      for (int q = 0; q < 4; ++q) ga[q] = G4[jb + wjg + 16 * q];
    }
    {  // compute chunk c from buf[cur]
      const int jq = jg * 4;
      float4 wv[4], xv[4];
#pragma unroll
      for (int r = 0; r < 4; ++r)
        wv[r] = *(const float4*)&Ws[cur][(rg * 4 + r) * 68 + jq];
#pragma unroll
      for (int kk = 0; kk < 4; ++kk)
        xv[kk] = *(const float4*)&XsT[cur][(kg * 4 + kk) * 68 + jq];
#pragma unroll
      for (int r = 0; r < 4; ++r)
#pragma unroll
        for (int kk = 0; kk < 4; ++kk)
          acc[r][kk] += wv[r].x * xv[kk].x + wv[r].y * xv[kk].y +
                        wv[r].z * xv[kk].z + wv[r].w * xv[kk].w;
    }
    if (c < 24) {  // write-late into buf[nxt]
      XsT[nxt][(sq * 4 + 0) * 68 + sj] = xs.x;
      XsT[nxt][(sq * 4 + 1) * 68 + sj] = xs.y;
      XsT[nxt][(sq * 4 + 2) * 68 + sj] = xs.z;
      XsT[nxt][(sq * 4 + 3) * 68 + sj] = xs.w;
#pragma unroll
      for (int q = 0; q < 4; ++q)
        Ws[nxt][wil * 68 + wjg + 16 * q] =
            fmaxf(fx * ga[q].x + fy * ga[q].y + fz * ga[q].z, 0.f);
    }
    __syncthreads();
  }

  // epilogue: reduce the 16 jg-groups, apply 0.5*x + 0.5*R*sv, plain store
#pragma unroll
  for (int r = 0; r < 4; ++r)
#pragma unroll
    for (int kk = 0; kk < 4; ++kk)
      Red[jg * 264 + (rg * 4 + r) * 16 + (kg * 4 + kk)] = acc[r][kk];
  __syncthreads();
  {
    const int il = t >> 4, kl = t & 15;
    float sv = 0.f;
#pragma unroll
    for (int g = 0; g < 16; ++g) sv += Red[g * 264 + il * 16 + kl];
    const int gi = i0 + il, gk = kbase + kl;
    Xout[(size_t)gi * 32 + gk] =
        0.5f * Xin[(size_t)gi * 32 + gk] + 0.5f * R[gi] * sv;
  }
}

// ---------------- phase: gram (5 blocks, j-partials; consumers sum) ---------
__global__ void __launch_bounds__(256)
k_gram(const float* __restrict__ Xa, const float* __restrict__ Xb,
       float* __restrict__ GPp) {
  __shared__ float sA[2048];
  __shared__ float sB[2048];
  const int bx = blockIdx.x, t = threadIdx.x;
  float acc[4] = {0.f, 0.f, 0.f, 0.f};
  for (int c = 0; c < 5; ++c) {
    const int j0 = bx * 320 + c * 64;
    __syncthreads();
    for (int s = t; s < 2048; s += 256) {
      sA[s] = Xa[(size_t)j0 * 32 + s];
      sB[s] = Xb[(size_t)j0 * 32 + s];
    }
    __syncthreads();
#pragma unroll
    for (int s = 0; s < 4; ++s) {
      int e = s * 256 + t;
      int a = e >> 5, b = e & 31;
      float sum = 0.f;
#pragma unroll 8
      for (int jl = 0; jl < 64; ++jl) sum += sA[jl * 32 + a] * sB[jl * 32 + b];
      acc[s] += sum;
    }
  }
#pragma unroll
  for (int s = 0; s < 4; ++s) GPp[(size_t)bx * 1024 + s * 256 + t] = acc[s];
}

// ---------------- phase: apply (200 blocks): chol + register trisolve -------
// Cholesky runs on wave 0 only, barrier-free (wave-lockstep; LDS ops are
// program-ordered within a wave). Round-5 version paid 32x4 = 128
// __syncthreads across 8 waves for the same serial work.
__global__ void __launch_bounds__(256)
k_apply(const float* __restrict__ GPp, const float* __restrict__ Xin,
        float* __restrict__ Xout) {
  __shared__ float Gm[32 * 33];
  const int bx = blockIdx.x, t = threadIdx.x;
#pragma unroll
  for (int u = 0; u < 4; ++u) {
    int e = t + u * 256;
    float g = 0.f;
#pragma unroll
    for (int p = 0; p < 5; ++p) g += GPp[p * 1024 + e];
    Gm[(e >> 5) * 33 + (e & 31)] = g;
  }
  const int r = t >> 5, l = t & 31;
  const int row = bx * 8 + r;
  float x = Xin[(size_t)row * M + l];
  __syncthreads();
  if (t < 64) {  // single-wave Cholesky, no barriers
    for (int k = 0; k < 32; ++k) {
      if (t == k) Gm[k * 33 + k] = sqrtf(fmaxf(Gm[k * 33 + k], 1e-30f));
      float piv = Gm[k * 33 + k];
      if (t > k && t < 32) Gm[t * 33 + k] /= piv;
#pragma unroll
      for (int u = 0; u < 16; ++u) {
        int e = t + u * 64;
        int i = e >> 5, j = e & 31;
        if (i > k && j > k && j <= i)
          Gm[i * 33 + j] -= Gm[i * 33 + k] * Gm[j * 33 + k];
      }
    }
  }
  __syncthreads();
  const int half = t & 32;
  float y = 0.f;
  for (int k = 0; k < 32; ++k) {
    float gkl = Gm[k * 33 + l];
    float contrib = (l < k) ? y * gkl : 0.f;
#pragma unroll
    for (int o = 16; o; o >>= 1) contrib += __shfl_xor(contrib, o, 64);
    float xk = __shfl(x, half + k, 64);
    float yk = (xk - contrib) / Gm[k * 33 + k];
    if (l == k) y = yk;
  }
  Xout[(size_t)row * M + l] = y;
}

// ---------------- wave reductions (rr) --------------------------------------
__device__ __forceinline__ float wred(float v) {
#pragma unroll
  for (int o = 32; o; o >>= 1) v += __shfl_xor(v, o, 64);
  return v;
}
__device__ __forceinline__ float wredmin(float v) {
#pragma unroll
  for (int o = 32; o; o >>= 1) v = fminf(v, __shfl_xor(v, o, 64));
  return v;
}
__device__ __forceinline__ float wredmax(float v) {
#pragma unroll
  for (int o = 32; o; o >>= 1) v = fmaxf(v, __shfl_xor(v, o, 64));
  return v;
}

// ---------------- phase: rr (1 block x 1 wave) ------------------------------
// Round-5 evidence: 88us at ~7% of one CU's VALU = exposed LDS latency from
// NON-UNROLLED serial loops (row-dot 31x130cy x30 iters ~50us, rank-2 ~25us).
// Fix: static trip counts + full unroll so loads pipeline. Row-dot reads a
// fixed 31-wide window; vvs[j>=m]=0 masks the tail (Bs padded+zeroed so
// overreads are finite*0 = 0).
__global__ void __launch_bounds__(64)
k_rr(const float* __restrict__ GPp, const int* __restrict__ flags,
     const int* __restrict__ Kptr, float* __restrict__ out) {
  __shared__ float Bs[1088];   // 1056 + 32 zeroed pad (overread window)
  __shared__ float part[1024];
  __shared__ float vvs[32];
  __shared__ float uus[32];
  __shared__ float dd[32];
  __shared__ float ee[32];
  __shared__ float ee2[32];
  __shared__ float evs[32];
  const int t = threadIdx.x;  // 0..63
#pragma unroll
  for (int u = 0; u < 16; ++u) {
    int e = t + u * 64;
    float g = 0.f;
#pragma unroll
    for (int p = 0; p < 5; ++p) g += GPp[p * 1024 + e];
    part[e] = g;
  }
  if (t < 32) Bs[1056 + t] = 0.f;  // finite pad for row-dot overread
  __syncthreads();
#pragma unroll
  for (int u = 0; u < 16; ++u) {
    int e = t + u * 64;
    int i = e >> 5, j = e & 31;
    Bs[i * 33 + j] = 0.5f * (part[e] + part[j * 32 + i]);
  }
  __syncthreads();
  for (int k = 0; k <= 29; ++k) {
    const int m = 31 - k;
    float xi = (t < m) ? Bs[(k + 1 + t) * 33 + k] : 0.f;
    float nx2 = wred(xi * xi);
    float x0 = __shfl(xi, 0, 64);
    if (nx2 < 1e-28f) {
      if (t == 0) ee[k] = x0;
      __syncthreads();
      continue;
    }
    float alpha = (x0 >= 0.f) ? -sqrtf(nx2) : sqrtf(nx2);
    float h = nx2 - alpha * x0;
    float vi = (t < m) ? ((t == 0) ? (xi - alpha) : xi) : 0.f;
    if (t < 32) vvs[t] = vi;
    if (t == 0) ee[k] = alpha;
    __syncthreads();
    float pi = 0.f;
    if (t < m) {
      const float* rowp = &Bs[(k + 1 + t) * 33 + (k + 1)];
#pragma unroll
      for (int j = 0; j < 31; ++j) pi += rowp[j] * vvs[j];  // vvs[j>=m]=0
      pi /= h;
    }
    float vp = wred((t < 32) ? vi * pi : 0.f);
    float Kc = vp / (2.f * h);
    if (t < 32) uus[t] = (t < m) ? (pi - Kc * vi) : 0.f;
    __syncthreads();
#pragma unroll
    for (int u = 0; u < 16; ++u) {
      int e = t + u * 64;
      int i = e >> 5, j = e & 31;
      if (i < m && j < m)
        Bs[(k + 1 + i) * 33 + (k + 1 + j)] -= vvs[i] * uus[j] + uus[i] * vvs[j];
    }
    __syncthreads();
  }
  if (t < 32) dd[t] = Bs[t * 33 + t];
  if (t == 0) { ee[30] = Bs[31 * 33 + 30]; ee[31] = 0.f; }
  __syncthreads();
  if (t < 32) ee2[t] = (t < 31) ? ee[t] * ee[t] : 0.f;
  __syncthreads();
  float lo, hi;
  {
    int tt = t & 31;
    float di = dd[tt];
    float r = 0.f;
    if (tt > 0) r += fabsf(ee[tt - 1]);
    if (tt < 31) r += fabsf(ee[tt]);
    lo = wredmin(di - r) - 1e-6f;
    hi = wredmax(di + r) + 1e-6f;
  }
  if (t < 32) {
    // tridiagonal in registers: the Sturm chain is serial; LDS reads inside
    // it would expose ~120cy each
    float ddr[32], ee2r[31];
#pragma unroll
    for (int i2 = 0; i2 < 32; ++i2) ddr[i2] = dd[i2];
#pragma unroll
    for (int i2 = 0; i2 < 31; ++i2) ee2r[i2] = ee2[i2];
    float a = lo, b = hi;
    for (int it = 0; it < BIS_IT; ++it) {
      float mid = 0.5f * (a + b);
      float q = ddr[0] - mid;
      int cnt = (q < 0.f) ? 1 : 0;
#pragma unroll
      for (int i = 1; i < 32; ++i) {
        float den = q;
        float ad = fabsf(den);
        den = (ad < 1e-30f) ? ((den < 0.f) ? -1e-30f : 1e-30f) : den;
        q = ddr[i] - mid - ee2r[i - 1] * __builtin_amdgcn_rcpf(den);
        cnt += (q < 0.f) ? 1 : 0;
      }
      if (cnt <= t) a = mid; else b = mid;
    }
    evs[t] = 0.5f * (a + b);
  }
  __syncthreads();
  if (t == 0) {
    int K = Kptr ? *Kptr : 10;
    if (K < 1) K = 10;
    if (K > 32) K = 32;
    float t12 = 0.f, t13 = 0.f, t23 = 0.f;
    for (int b = 0; b < 8; ++b) {
      float f1 = flags[b * 2 + 0] ? 1.f : 0.f;
      float f2 = flags[b * 2 + 1] ? 1.f : 0.f;
      for (int k = 0; k < K; ++k) {
        float v1 = (k == 0) ? 0.f : (k == 1 ? f1 : 1.f);
        float v2 = (k == 0) ? 0.f : (k == 1 ? f2 : 1.f);
        float m3 = 2.f - 2.f * evs[31 - k];
        t12 += (v1 - v2) * (v1 - v2);
        t13 += (v1 - m3) * (v1 - m3);
        t23 += (v2 - m3) * (v2 - m3);
      }
    }
    out[0] = 5.f * (t12 + t13 + t23) / (8.f * (float)K);
  }
}

// ---------------- host: 30 sequential launches ------------------------------
extern "C" void kernel_launch(void* const* d_in, const int* in_sizes, int n_in,
                              void* d_out, int out_size, void* d_ws, size_t ws_size,
                              hipStream_t stream) {
  const float* feats = (const float*)d_in[0];
  const int* Kptr = (n_in > 1) ? (const int*)d_in[1] : nullptr;
  float* ws = (float*)d_ws;
  float* RZ = ws;                         // 38400
  float* F  = ws + 38400;                 // 4800
  float* G4f = ws + 43200;                // 6400 (1600 float4)
  float* R  = ws + 49600;                 // 1600
  int* FLAGS = (int*)(ws + 51200);        // 16 ints (64 reserved)
  float* GP = ws + 51264;                 // 3 x 5 x 1024 partials
  float* XB = ws + 51264 + 15360;         // 4 x XSZ ring
  float* bufs[4] = {XB, XB + XSZ, XB + 2 * XSZ, XB + 3 * XSZ};
  const float4* G4 = (const float4*)G4f;
  float* outp = (float*)d_out;

  k_resize<<<dim3(168), dim3(256), 0, stream>>>(feats, RZ);
  k_prep<<<dim3(23), dim3(256), 0, stream>>>(RZ, F, FLAGS);
  k_degree<<<dim3(100), dim3(256), 0, stream>>>(F, R, G4f, bufs[0]);

  const float* cur = bufs[0];
  for (int m = 1; m <= 10; ++m) {
    float* o = bufs[1 + m % 3];
    k_mv<<<dim3(200), dim3(256), 0, stream>>>(F, G4, R, cur, o);
    cur = o;
  }
  k_gram<<<dim3(5), dim3(256), 0, stream>>>(cur, cur, GP);
  k_apply<<<dim3(200), dim3(256), 0, stream>>>(GP, cur, bufs[0]);  // XV1
  cur = bufs[0];
  for (int m = 11; m <= 20; ++m) {
    float* o = bufs[1 + m % 3];
    k_mv<<<dim3(200), dim3(256), 0, stream>>>(F, G4, R, cur, o);
    cur = o;
  }
  k_gram<<<dim3(5), dim3(256), 0, stream>>>(cur, cur, GP + 5120);
  k_apply<<<dim3(200), dim3(256), 0, stream>>>(GP + 5120, cur, bufs[0]);  // XV2
  k_mv<<<dim3(200), dim3(256), 0, stream>>>(F, G4, R, bufs[0], bufs[1]);  // X21
  k_gram<<<dim3(5), dim3(256), 0, stream>>>(bufs[0], bufs[1], GP + 10240);
  k_rr<<<dim3(1), dim3(64), 0, stream>>>(GP + 10240, FLAGS, Kptr, outp);
}

// Round 7
// 542.594 us; speedup vs baseline: 1.0871x; 1.0871x over previous
//
#include <hip/hip_runtime.h>
#include <math.h>

#define N16 1600
#define M 32
#define XSZ 51200
#define BIS_IT 28
#define EPSF 1e-12f

// Cross-phase communication relies on kernel-boundary coherence (sequential
// launches). No device-scope atomics/stores (round-0: agent-scope ops caused
// 35x write-through amplification, 479 MB/solve).

// ---------------- phase: resize (168 blocks) --------------------------------
__device__ void taps1d(int o, int* lo, int* hi, float* wsum, float w[8]) {
  int l = 4 * o - 2, h = 4 * o + 5;
  if (l < 0) l = 0;
  if (h > 159) h = 159;
  float c = 4.f * o + 1.5f, s = 0.f;
  for (int x = l; x <= h; ++x) {
    float ww = 1.f - fabsf((float)x - c) * 0.25f;
    w[x - l] = ww;
    s += ww;
  }
  *lo = l; *hi = h; *wsum = s;
}

__global__ void __launch_bounds__(256)
k_resize(const float* __restrict__ in, float* __restrict__ rz) {
  const int bx = blockIdx.x, t = threadIdx.x;
  int map = bx / 7;
  int o = (bx % 7) * 256 + t;
  if (o >= N16) return;
  int oy = o / 40, ox = o % 40;
  int ly, hy, lx, hx; float sy, sx; float wy[8], wx[8];
  taps1d(oy, &ly, &hy, &sy, wy);
  taps1d(ox, &lx, &hx, &sx, wx);
  const float* src = in + (size_t)map * 160 * 160;
  float acc = 0.f;
  for (int y = ly; y <= hy; ++y) {
    float a = 0.f;
    const float* row = src + y * 160;
    for (int x = lx; x <= hx; ++x) a += wx[x - lx] * row[x];
    acc += wy[y - ly] * a;
  }
  rz[map * N16 + o] = acc / (sy * sx);
}

// ---------------- phase: prep (23 blocks) -----------------------------------
__global__ void __launch_bounds__(256)
k_prep(const float* __restrict__ rz, float* __restrict__ F,
       int* __restrict__ flags) {
  __shared__ int sp[256];
  __shared__ int sn[256];
  const int bx = blockIdx.x, t = threadIdx.x;
  if (bx < 16) {
    int b = bx >> 1, c = bx & 1;
    const float* m = rz + (b * 3 + c) * N16;
    int cp = 0, cn = 0;
    for (int o = t; o < N16; o += 256) {
      float v = m[o];
      cp += (v > 0.f);
      cn += (v < 0.f);
    }
    sp[t] = cp; sn[t] = cn;
    __syncthreads();
    for (int s = 128; s > 0; s >>= 1) {
      if (t < s) { sp[t] += sp[t + s]; sn[t] += sn[t + s]; }
      __syncthreads();
    }
    if (t == 0) flags[bx] = (sp[0] == 0 || sn[0] == 0) ? 1 : 0;
  } else {
    int n = (bx - 16) * 256 + t;
    if (n < N16) {
      float x = rz[n], y = rz[N16 + n], z = rz[2 * N16 + n];
      float nrm = sqrtf(x * x + y * y + z * z);
      float s = 1.f / fmaxf(nrm, EPSF);
      F[n * 3 + 0] = x * s;
      F[n * 3 + 1] = y * s;
      F[n * 3 + 2] = z * s;
    }
  }
}

// ---------------- phase: degree + G4 + X0 init (100 blocks) -----------------
__global__ void __launch_bounds__(256)
k_degree(const float* __restrict__ F, float* __restrict__ R,
         float* __restrict__ G4f, float* __restrict__ X0) {
  __shared__ float Fl[4800];
  __shared__ float red[256];
  const int bx = blockIdx.x, t = threadIdx.x;
  for (int s = t; s < 4800; s += 256) Fl[s] = F[s];
  __syncthreads();
  int rl = t >> 4, jt = t & 15;
  int i = bx * 16 + rl;
  float fx = Fl[i * 3], fy = Fl[i * 3 + 1], fz = Fl[i * 3 + 2];
  float s = 0.f;
#pragma unroll 8
  for (int j = jt; j < N16; j += 16) {
    float w = fx * Fl[j * 3] + fy * Fl[j * 3 + 1] + fz * Fl[j * 3 + 2];
    if (w > 0.f) s += w;
  }
  red[t] = s;
  __syncthreads();
  for (int st = 8; st > 0; st >>= 1) {
    if (jt < st) red[t] += red[t + st];
    __syncthreads();
  }
  if (jt == 0) {
    float d = red[t];
    if (d < EPSF) d = 1.f;
    float r = rsqrtf(d);
    R[i] = r;
    G4f[i * 4 + 0] = r * fx;
    G4f[i * 4 + 1] = r * fy;
    G4f[i * 4 + 2] = r * fz;
    G4f[i * 4 + 3] = 0.f;
  }
  for (int e = t; e < 512; e += 256) {
    int n = bx * 16 + (e >> 5);
    int k = e & 31;
    unsigned u = ((unsigned)n * 2654435761u) ^ ((unsigned)k * 0x9E3779B9u);
    u = u * 1664525u + 1013904223u;
    u ^= u >> 16; u *= 2246822519u; u ^= u >> 13;
    X0[n * M + k] = ((float)(u >> 8) * (1.f / 8388608.f)) - 1.f;
  }
}

// ---------------- phase: MV (400 blocks = 200 i-groups x 2 k-halves) --------
// Round-6 evidence: 200 blocks = <=1 wave/SIMD device-wide, all LDS/barrier
// latency exposed (~16us/MV vs ~6us throughput model). 400 blocks -> ~2
// waves/SIMD on most CUs. Block owns 8 i-rows x 16 k-cols, full j sum: one
// plain store per output. Same chunk pipeline and j-group summation order as
// the verified 16-row version (numerics identical).
__global__ void __launch_bounds__(256)
k_mv(const float* __restrict__ F, const float4* __restrict__ G4,
     const float* __restrict__ R, const float* __restrict__ Xin,
     float* __restrict__ Xout) {
  __shared__ float Ws[2][544];     // [8 i][68] per buffer
  __shared__ float XsT[2][1088];   // [16 k][68] per buffer (transposed X)
  __shared__ float Red[16 * 136];  // 16 jg pages x (8 i x 16 k), padded
  const int bx = blockIdx.x, t = threadIdx.x;
  const int ig = bx >> 1, kh = bx & 1;
  const int i0 = ig * 8, kbase = kh * 16;
  const int rg = t & 3, kg = (t >> 2) & 3, jg = t >> 4;  // compute: 4x4x16
  const int sj = t >> 2, sq = t & 3;                     // X stage: 64 j x 4 q
  const int wil = t & 7, wjg = t >> 3;                   // W stage: 8 i x 32 j
  const float fx = F[(i0 + wil) * 3 + 0];
  const float fy = F[(i0 + wil) * 3 + 1];
  const float fz = F[(i0 + wil) * 3 + 2];

  float acc[2][4];
#pragma unroll
  for (int r = 0; r < 2; ++r)
#pragma unroll
    for (int kk = 0; kk < 4; ++kk) acc[r][kk] = 0.f;

  // prologue: stage chunk 0 into buffer 0
  {
    float4 xs = ((const float4*)Xin)[(size_t)sj * 8 + kh * 4 + sq];
    XsT[0][(sq * 4 + 0) * 68 + sj] = xs.x;
    XsT[0][(sq * 4 + 1) * 68 + sj] = xs.y;
    XsT[0][(sq * 4 + 2) * 68 + sj] = xs.z;
    XsT[0][(sq * 4 + 3) * 68 + sj] = xs.w;
#pragma unroll
    for (int q = 0; q < 2; ++q) {
      float4 g = G4[wjg + 32 * q];
      Ws[0][wil * 68 + wjg + 32 * q] =
          fmaxf(fx * g.x + fy * g.y + fz * g.z, 0.f);
    }
  }
  __syncthreads();

  for (int c = 0; c < 25; ++c) {
    const int cur = c & 1, nxt = cur ^ 1;
    float4 xs = {0.f, 0.f, 0.f, 0.f};
    float4 ga[2];
    if (c < 24) {  // issue next-chunk loads early
      const int jb = (c + 1) * 64;
      xs = ((const float4*)Xin)[(size_t)(jb + sj) * 8 + kh * 4 + sq];
#pragma unroll
      for (int q = 0; q < 2; ++q) ga[q] = G4[jb + wjg + 32 * q];
    }
    {  // compute chunk c from buf[cur]
      const int jq = jg * 4;
      float4 wv[2], xv[4];
#pragma unroll
      for (int r = 0; r < 2; ++r)
        wv[r] = *(const float4*)&Ws[cur][(rg * 2 + r) * 68 + jq];
#pragma unroll
      for (int kk = 0; kk < 4; ++kk)
        xv[kk] = *(const float4*)&XsT[cur][(kg * 4 + kk) * 68 + jq];
#pragma unroll
      for (int r = 0; r < 2; ++r)
#pragma unroll
        for (int kk = 0; kk < 4; ++kk)
          acc[r][kk] += wv[r].x * xv[kk].x + wv[r].y * xv[kk].y +
                        wv[r].z * xv[kk].z + wv[r].w * xv[kk].w;
    }
    if (c < 24) {  // write-late into buf[nxt]
      XsT[nxt][(sq * 4 + 0) * 68 + sj] = xs.x;
      XsT[nxt][(sq * 4 + 1) * 68 + sj] = xs.y;
      XsT[nxt][(sq * 4 + 2) * 68 + sj] = xs.z;
      XsT[nxt][(sq * 4 + 3) * 68 + sj] = xs.w;
#pragma unroll
      for (int q = 0; q < 2; ++q)
        Ws[nxt][wil * 68 + wjg + 32 * q] =
            fmaxf(fx * ga[q].x + fy * ga[q].y + fz * ga[q].z, 0.f);
    }
    __syncthreads();
  }

  // epilogue: reduce 16 jg-pages, apply 0.5*x + 0.5*R*sv, plain store
#pragma unroll
  for (int r = 0; r < 2; ++r)
#pragma unroll
    for (int kk = 0; kk < 4; ++kk)
      Red[jg * 136 + (rg * 2 + r) * 16 + (kg * 4 + kk)] = acc[r][kk];
  __syncthreads();
  if (t < 128) {
    const int il = t >> 4, kl = t & 15;
    float sv = 0.f;
#pragma unroll
    for (int g = 0; g < 16; ++g) sv += Red[g * 136 + il * 16 + kl];
    const int gi = i0 + il, gk = kbase + kl;
    Xout[(size_t)gi * 32 + gk] =
        0.5f * Xin[(size_t)gi * 32 + gk] + 0.5f * R[gi] * sv;
  }
}

// ---------------- phase: gram (5 blocks, j-partials; consumers sum) ---------
__global__ void __launch_bounds__(256)
k_gram(const float* __restrict__ Xa, const float* __restrict__ Xb,
       float* __restrict__ GPp) {
  __shared__ float sA[2048];
  __shared__ float sB[2048];
  const int bx = blockIdx.x, t = threadIdx.x;
  float acc[4] = {0.f, 0.f, 0.f, 0.f};
  for (int c = 0; c < 5; ++c) {
    const int j0 = bx * 320 + c * 64;
    __syncthreads();
    for (int s = t; s < 2048; s += 256) {
      sA[s] = Xa[(size_t)j0 * 32 + s];
      sB[s] = Xb[(size_t)j0 * 32 + s];
    }
    __syncthreads();
#pragma unroll
    for (int s = 0; s < 4; ++s) {
      int e = s * 256 + t;
      int a = e >> 5, b = e & 31;
      float sum = 0.f;
#pragma unroll 8
      for (int jl = 0; jl < 64; ++jl) sum += sA[jl * 32 + a] * sB[jl * 32 + b];
      acc[s] += sum;
    }
  }
#pragma unroll
  for (int s = 0; s < 4; ++s) GPp[(size_t)bx * 1024 + s * 256 + t] = acc[s];
}

// ---------------- phase: apply (200 blocks): chol + register trisolve -------
__global__ void __launch_bounds__(256)
k_apply(const float* __restrict__ GPp, const float* __restrict__ Xin,
        float* __restrict__ Xout) {
  __shared__ float Gm[32 * 33];
  const int bx = blockIdx.x, t = threadIdx.x;
#pragma unroll
  for (int u = 0; u < 4; ++u) {
    int e = t + u * 256;
    float g = 0.f;
#pragma unroll
    for (int p = 0; p < 5; ++p) g += GPp[p * 1024 + e];
    Gm[(e >> 5) * 33 + (e & 31)] = g;
  }
  const int r = t >> 5, l = t & 31;
  const int row = bx * 8 + r;
  float x = Xin[(size_t)row * M + l];
  __syncthreads();
  if (t < 64) {  // single-wave Cholesky, no barriers (wave-ordered LDS)
    for (int k = 0; k < 32; ++k) {
      if (t == k) Gm[k * 33 + k] = sqrtf(fmaxf(Gm[k * 33 + k], 1e-30f));
      float piv = Gm[k * 33 + k];
      if (t > k && t < 32) Gm[t * 33 + k] /= piv;
#pragma unroll
      for (int u = 0; u < 16; ++u) {
        int e = t + u * 64;
        int i = e >> 5, j = e & 31;
        if (i > k && j > k && j <= i)
          Gm[i * 33 + j] -= Gm[i * 33 + k] * Gm[j * 33 + k];
      }
    }
  }
  __syncthreads();
  const int half = t & 32;
  float y = 0.f;
  for (int k = 0; k < 32; ++k) {
    float gkl = Gm[k * 33 + l];
    float contrib = (l < k) ? y * gkl : 0.f;
#pragma unroll
    for (int o = 16; o; o >>= 1) contrib += __shfl_xor(contrib, o, 64);
    float xk = __shfl(x, half + k, 64);
    float yk = (xk - contrib) / Gm[k * 33 + k];
    if (l == k) y = yk;
  }
  Xout[(size_t)row * M + l] = y;
}

// ---------------- wave reductions (rr) --------------------------------------
__device__ __forceinline__ float wred(float v) {
#pragma unroll
  for (int o = 32; o; o >>= 1) v += __shfl_xor(v, o, 64);
  return v;
}
__device__ __forceinline__ float wredmin(float v) {
#pragma unroll
  for (int o = 32; o; o >>= 1) v = fminf(v, __shfl_xor(v, o, 64));
  return v;
}
__device__ __forceinline__ float wredmax(float v) {
#pragma unroll
  for (int o = 32; o; o >>= 1) v = fmaxf(v, __shfl_xor(v, o, 64));
  return v;
}

// ---------------- phase: rr (1 block x 1 wave) ------------------------------
// Round-6 lesson: interleaved LDS-load+use exposes ~130cy per element pair
// (113us). Fix: FORCE batching — load the full 32-float row and the v/u
// vectors into static-indexed register arrays (one waitcnt per batch), then
// pure-FMA dot and rank-2 (row reused from registers). Global-index masking:
// vg/ug are exactly 0 outside the active range, so full-width updates leave
// inactive rows/cols bit-identical (added terms are exact +0).
__global__ void __launch_bounds__(64)
k_rr(const float* __restrict__ GPp, const int* __restrict__ flags,
     const int* __restrict__ Kptr, float* __restrict__ out) {
  __shared__ float Bs[1056];
  __shared__ float part[1024];
  __shared__ float vgs[32];
  __shared__ float uus[32];
  __shared__ float dd[32];
  __shared__ float ee[32];
  __shared__ float ee2[32];
  __shared__ float evs[32];
  const int t = threadIdx.x;  // 0..63
#pragma unroll
  for (int u = 0; u < 16; ++u) {
    int e = t + u * 64;
    float g = 0.f;
#pragma unroll
    for (int p = 0; p < 5; ++p) g += GPp[p * 1024 + e];
    part[e] = g;
  }
  __syncthreads();
#pragma unroll
  for (int u = 0; u < 16; ++u) {
    int e = t + u * 64;
    int i = e >> 5, j = e & 31;
    Bs[i * 33 + j] = 0.5f * (part[e] + part[j * 32 + i]);
  }
  __syncthreads();
  for (int k = 0; k <= 29; ++k) {
    float xi = (t > k && t < 32) ? Bs[t * 33 + k] : 0.f;  // active rows only
    float nx2 = wred(xi * xi);
    float x0 = __shfl(xi, k + 1, 64);
    if (nx2 < 1e-28f) {
      if (t == 0) ee[k] = x0;
      __syncthreads();
      continue;
    }
    float alpha = (x0 >= 0.f) ? -sqrtf(nx2) : sqrtf(nx2);
    float h = nx2 - alpha * x0;
    float vg = (t == k + 1) ? (xi - alpha) : xi;  // 0 outside active rows
    if (t < 32) vgs[t] = vg;
    if (t == 0) ee[k] = alpha;
    __syncthreads();
    float rv[32], vgr[32];
    float pi = 0.f;
    if (t < 32) {
#pragma unroll
      for (int c = 0; c < 32; ++c) rv[c] = Bs[t * 33 + c];   // batched row
#pragma unroll
      for (int c = 0; c < 32; ++c) vgr[c] = vgs[c];          // broadcast
#pragma unroll
      for (int c = 0; c < 32; ++c) pi += rv[c] * vgr[c];     // pure FMA
      pi /= h;
    }
    float vp = wred((t < 32) ? vg * pi : 0.f);
    float Kc = vp / (2.f * h);
    float ug = (t > k && t < 32) ? (pi - Kc * vg) : 0.f;
    if (t < 32) uus[t] = ug;
    __syncthreads();
    if (t < 32) {
      float ugr[32];
#pragma unroll
      for (int c = 0; c < 32; ++c) ugr[c] = uus[c];
#pragma unroll
      for (int c = 0; c < 32; ++c)
        Bs[t * 33 + c] = rv[c] - (vg * ugr[c] + ug * vgr[c]);
    }
    __syncthreads();
  }
  if (t < 32) dd[t] = Bs[t * 33 + t];
  if (t == 0) { ee[30] = Bs[31 * 33 + 30]; ee[31] = 0.f; }
  __syncthreads();
  if (t < 32) ee2[t] = (t < 31) ? ee[t] * ee[t] : 0.f;
  __syncthreads();
  float lo, hi;
  {
    int tt = t & 31;
    float di = dd[tt];
    float r = 0.f;
    if (tt > 0) r += fabsf(ee[tt - 1]);
    if (tt < 31) r += fabsf(ee[tt]);
    lo = wredmin(di - r) - 1e-6f;
    hi = wredmax(di + r) + 1e-6f;
  }
  if (t < 32) {
    float ddr[32], ee2r[31];
#pragma unroll
    for (int i2 = 0; i2 < 32; ++i2) ddr[i2] = dd[i2];
#pragma unroll
    for (int i2 = 0; i2 < 31; ++i2) ee2r[i2] = ee2[i2];
    float a = lo, b = hi;
    for (int it = 0; it < BIS_IT; ++it) {
      float mid = 0.5f * (a + b);
      float q = ddr[0] - mid;
      int cnt = (q < 0.f) ? 1 : 0;
#pragma unroll
      for (int i = 1; i < 32; ++i) {
        float den = q;
        float ad = fabsf(den);
        den = (ad < 1e-30f) ? ((den < 0.f) ? -1e-30f : 1e-30f) : den;
        q = ddr[i] - mid - ee2r[i - 1] * __builtin_amdgcn_rcpf(den);
        cnt += (q < 0.f) ? 1 : 0;
      }
      if (cnt <= t) a = mid; else b = mid;
    }
    evs[t] = 0.5f * (a + b);
  }
  __syncthreads();
  if (t == 0) {
    int K = Kptr ? *Kptr : 10;
    if (K < 1) K = 10;
    if (K > 32) K = 32;
    float t12 = 0.f, t13 = 0.f, t23 = 0.f;
    for (int b = 0; b < 8; ++b) {
      float f1 = flags[b * 2 + 0] ? 1.f : 0.f;
      float f2 = flags[b * 2 + 1] ? 1.f : 0.f;
      for (int k = 0; k < K; ++k) {
        float v1 = (k == 0) ? 0.f : (k == 1 ? f1 : 1.f);
        float v2 = (k == 0) ? 0.f : (k == 1 ? f2 : 1.f);
        float m3 = 2.f - 2.f * evs[31 - k];
        t12 += (v1 - v2) * (v1 - v2);
        t13 += (v1 - m3) * (v1 - m3);
        t23 += (v2 - m3) * (v2 - m3);
      }
    }
    out[0] = 5.f * (t12 + t13 + t23) / (8.f * (float)K);
  }
}

// ---------------- host: 30 sequential launches ------------------------------
extern "C" void kernel_launch(void* const* d_in, const int* in_sizes, int n_in,
                              void* d_out, int out_size, void* d_ws, size_t ws_size,
                              hipStream_t stream) {
  const float* feats = (const float*)d_in[0];
  const int* Kptr = (n_in > 1) ? (const int*)d_in[1] : nullptr;
  float* ws = (float*)d_ws;
  float* RZ = ws;                         // 38400
  float* F  = ws + 38400;                 // 4800
  float* G4f = ws + 43200;                // 6400 (1600 float4)
  float* R  = ws + 49600;                 // 1600
  int* FLAGS = (int*)(ws + 51200);        // 16 ints (64 reserved)
  float* GP = ws + 51264;                 // 3 x 5 x 1024 partials
  float* XB = ws + 51264 + 15360;         // 4 x XSZ ring
  float* bufs[4] = {XB, XB + XSZ, XB + 2 * XSZ, XB + 3 * XSZ};
  const float4* G4 = (const float4*)G4f;
  float* outp = (float*)d_out;

  k_resize<<<dim3(168), dim3(256), 0, stream>>>(feats, RZ);
  k_prep<<<dim3(23), dim3(256), 0, stream>>>(RZ, F, FLAGS);
  k_degree<<<dim3(100), dim3(256), 0, stream>>>(F, R, G4f, bufs[0]);

  const float* cur = bufs[0];
  for (int m = 1; m <= 10; ++m) {
    float* o = bufs[1 + m % 3];
    k_mv<<<dim3(400), dim3(256), 0, stream>>>(F, G4, R, cur, o);
    cur = o;
  }
  k_gram<<<dim3(5), dim3(256), 0, stream>>>(cur, cur, GP);
  k_apply<<<dim3(200), dim3(256), 0, stream>>>(GP, cur, bufs[0]);  // XV1
  cur = bufs[0];
  for (int m = 11; m <= 20; ++m) {
    float* o = bufs[1 + m % 3];
    k_mv<<<dim3(400), dim3(256), 0, stream>>>(F, G4, R, cur, o);
    cur = o;
  }
  k_gram<<<dim3(5), dim3(256), 0, stream>>>(cur, cur, GP + 5120);
  k_apply<<<dim3(200), dim3(256), 0, stream>>>(GP + 5120, cur, bufs[0]);  // XV2
  k_mv<<<dim3(400), dim3(256), 0, stream>>>(F, G4, R, bufs[0], bufs[1]);  // X21
  k_gram<<<dim3(5), dim3(256), 0, stream>>>(bufs[0], bufs[1], GP + 10240);
  k_rr<<<dim3(1), dim3(64), 0, stream>>>(GP + 10240, FLAGS, Kptr, outp);
}

// Round 8
// 502.802 us; speedup vs baseline: 1.1732x; 1.0791x over previous
//
#include <hip/hip_runtime.h>
#include <math.h>

#define N16 1600
#define M 32
#define XSZ 51200
#define BIS_IT 28
#define EPSF 1e-12f

// Cross-phase communication relies on kernel-boundary coherence (sequential
// launches). No device-scope atomics/stores (round-0: agent-scope ops caused
// 35x write-through amplification, 479 MB/solve).

// ---------------- phase: resize (168 blocks) --------------------------------
__device__ void taps1d(int o, int* lo, int* hi, float* wsum, float w[8]) {
  int l = 4 * o - 2, h = 4 * o + 5;
  if (l < 0) l = 0;
  if (h > 159) h = 159;
  float c = 4.f * o + 1.5f, s = 0.f;
  for (int x = l; x <= h; ++x) {
    float ww = 1.f - fabsf((float)x - c) * 0.25f;
    w[x - l] = ww;
    s += ww;
  }
  *lo = l; *hi = h; *wsum = s;
}

__global__ void __launch_bounds__(256)
k_resize(const float* __restrict__ in, float* __restrict__ rz) {
  const int bx = blockIdx.x, t = threadIdx.x;
  int map = bx / 7;
  int o = (bx % 7) * 256 + t;
  if (o >= N16) return;
  int oy = o / 40, ox = o % 40;
  int ly, hy, lx, hx; float sy, sx; float wy[8], wx[8];
  taps1d(oy, &ly, &hy, &sy, wy);
  taps1d(ox, &lx, &hx, &sx, wx);
  const float* src = in + (size_t)map * 160 * 160;
  float acc = 0.f;
  for (int y = ly; y <= hy; ++y) {
    float a = 0.f;
    const float* row = src + y * 160;
    for (int x = lx; x <= hx; ++x) a += wx[x - lx] * row[x];
    acc += wy[y - ly] * a;
  }
  rz[map * N16 + o] = acc / (sy * sx);
}

// ---------------- phase: prep (23 blocks) -----------------------------------
__global__ void __launch_bounds__(256)
k_prep(const float* __restrict__ rz, float* __restrict__ F,
       int* __restrict__ flags) {
  __shared__ int sp[256];
  __shared__ int sn[256];
  const int bx = blockIdx.x, t = threadIdx.x;
  if (bx < 16) {
    int b = bx >> 1, c = bx & 1;
    const float* m = rz + (b * 3 + c) * N16;
    int cp = 0, cn = 0;
    for (int o = t; o < N16; o += 256) {
      float v = m[o];
      cp += (v > 0.f);
      cn += (v < 0.f);
    }
    sp[t] = cp; sn[t] = cn;
    __syncthreads();
    for (int s = 128; s > 0; s >>= 1) {
      if (t < s) { sp[t] += sp[t + s]; sn[t] += sn[t + s]; }
      __syncthreads();
    }
    if (t == 0) flags[bx] = (sp[0] == 0 || sn[0] == 0) ? 1 : 0;
  } else {
    int n = (bx - 16) * 256 + t;
    if (n < N16) {
      float x = rz[n], y = rz[N16 + n], z = rz[2 * N16 + n];
      float nrm = sqrtf(x * x + y * y + z * z);
      float s = 1.f / fmaxf(nrm, EPSF);
      F[n * 3 + 0] = x * s;
      F[n * 3 + 1] = y * s;
      F[n * 3 + 2] = z * s;
    }
  }
}

// ---------------- phase: degree + G4 + X0 init (100 blocks) -----------------
__global__ void __launch_bounds__(256)
k_degree(const float* __restrict__ F, float* __restrict__ R,
         float* __restrict__ G4f, float* __restrict__ X0) {
  __shared__ float Fl[4800];
  __shared__ float red[256];
  const int bx = blockIdx.x, t = threadIdx.x;
  for (int s = t; s < 4800; s += 256) Fl[s] = F[s];
  __syncthreads();
  int rl = t >> 4, jt = t & 15;
  int i = bx * 16 + rl;
  float fx = Fl[i * 3], fy = Fl[i * 3 + 1], fz = Fl[i * 3 + 2];
  float s = 0.f;
#pragma unroll 8
  for (int j = jt; j < N16; j += 16) {
    float w = fx * Fl[j * 3] + fy * Fl[j * 3 + 1] + fz * Fl[j * 3 + 2];
    if (w > 0.f) s += w;
  }
  red[t] = s;
  __syncthreads();
  for (int st = 8; st > 0; st >>= 1) {
    if (jt < st) red[t] += red[t + st];
    __syncthreads();
  }
  if (jt == 0) {
    float d = red[t];
    if (d < EPSF) d = 1.f;
    float r = rsqrtf(d);
    R[i] = r;
    G4f[i * 4 + 0] = r * fx;
    G4f[i * 4 + 1] = r * fy;
    G4f[i * 4 + 2] = r * fz;
    G4f[i * 4 + 3] = 0.f;
  }
  for (int e = t; e < 512; e += 256) {
    int n = bx * 16 + (e >> 5);
    int k = e & 31;
    unsigned u = ((unsigned)n * 2654435761u) ^ ((unsigned)k * 0x9E3779B9u);
    u = u * 1664525u + 1013904223u;
    u ^= u >> 16; u *= 2246822519u; u ^= u >> 13;
    X0[n * M + k] = ((float)(u >> 8) * (1.f / 8388608.f)) - 1.f;
  }
}

// ---------------- phase: MV (400 blocks = 200 i-groups x 2 k-halves) --------
// Round-7 evidence: MV time invariant under block-count changes -> cost is the
// 25-chunk serial barrier structure (~300cy compute per ~1000cy period), not
// parallelism. Fix: chunk 64 -> 320 j (5 chunks, 6 barriers vs 26). Thread
// j-sets and accumulation ORDER are bit-identical to round 7 (m = 5c+ss walks
// 0..24 in order). LDS 70 KB -> 2 blocks/CU (same occupancy as before).
__global__ void __launch_bounds__(256)
k_mv(const float* __restrict__ F, const float4* __restrict__ G4,
     const float* __restrict__ R, const float* __restrict__ Xin,
     float* __restrict__ Xout) {
  __shared__ float Ws[2][8 * 324];    // [8 i][324] per buffer (320 j + pad)
  __shared__ float XsT[2][16 * 324];  // [16 k][324] per buffer (transposed X)
  __shared__ float Red[16 * 136];     // 16 jg pages x (8 i x 16 k), padded
  const int bx = blockIdx.x, t = threadIdx.x;
  const int ig = bx >> 1, kh = bx & 1;
  const int i0 = ig * 8, kbase = kh * 16;
  const int rg = t & 3, kg = (t >> 2) & 3, jg = t >> 4;  // compute: 4x4x16
  const int sj = t >> 2, sq = t & 3;                     // X stage: 64 j x 4 q
  const int wil = t & 7, wjg = t >> 3;                   // W stage: 8 i x 32 j
  const float fx = F[(i0 + wil) * 3 + 0];
  const float fy = F[(i0 + wil) * 3 + 1];
  const float fz = F[(i0 + wil) * 3 + 2];
  const float4* Xin4 = (const float4*)Xin;

  float acc[2][4];
#pragma unroll
  for (int r = 0; r < 2; ++r)
#pragma unroll
    for (int kk = 0; kk < 4; ++kk) acc[r][kk] = 0.f;

  // prologue: stage chunk 0 (j = 0..319) into buffer 0
#pragma unroll
  for (int p = 0; p < 5; ++p) {
    float4 xs = Xin4[(size_t)(p * 64 + sj) * 8 + kh * 4 + sq];
    XsT[0][(sq * 4 + 0) * 324 + p * 64 + sj] = xs.x;
    XsT[0][(sq * 4 + 1) * 324 + p * 64 + sj] = xs.y;
    XsT[0][(sq * 4 + 2) * 324 + p * 64 + sj] = xs.z;
    XsT[0][(sq * 4 + 3) * 324 + p * 64 + sj] = xs.w;
  }
#pragma unroll
  for (int q = 0; q < 10; ++q) {
    float4 g = G4[wjg + 32 * q];
    Ws[0][wil * 324 + wjg + 32 * q] =
        fmaxf(fx * g.x + fy * g.y + fz * g.z, 0.f);
  }
  __syncthreads();

  for (int c = 0; c < 5; ++c) {
    const int cur = c & 1, nxt = cur ^ 1;
    float4 xsr[5];
    float4 gar[10];
    if (c < 4) {  // issue next-chunk loads early (hide under compute)
      const int jb = (c + 1) * 320;
#pragma unroll
      for (int p = 0; p < 5; ++p)
        xsr[p] = Xin4[(size_t)(jb + p * 64 + sj) * 8 + kh * 4 + sq];
#pragma unroll
      for (int q = 0; q < 10; ++q) gar[q] = G4[jb + wjg + 32 * q];
    }
    // compute chunk c from buf[cur]: 5 sub-steps of 64 j (order == round 7)
#pragma unroll
    for (int ss = 0; ss < 5; ++ss) {
      const int jq = ss * 64 + jg * 4;
      float4 wv[2], xv[4];
#pragma unroll
      for (int r = 0; r < 2; ++r)
        wv[r] = *(const float4*)&Ws[cur][(rg * 2 + r) * 324 + jq];
#pragma unroll
      for (int kk = 0; kk < 4; ++kk)
        xv[kk] = *(const float4*)&XsT[cur][(kg * 4 + kk) * 324 + jq];
#pragma unroll
      for (int r = 0; r < 2; ++r)
#pragma unroll
        for (int kk = 0; kk < 4; ++kk)
          acc[r][kk] += wv[r].x * xv[kk].x + wv[r].y * xv[kk].y +
                        wv[r].z * xv[kk].z + wv[r].w * xv[kk].w;
    }
    if (c < 4) {  // write-late into buf[nxt]
#pragma unroll
      for (int p = 0; p < 5; ++p) {
        XsT[nxt][(sq * 4 + 0) * 324 + p * 64 + sj] = xsr[p].x;
        XsT[nxt][(sq * 4 + 1) * 324 + p * 64 + sj] = xsr[p].y;
        XsT[nxt][(sq * 4 + 2) * 324 + p * 64 + sj] = xsr[p].z;
        XsT[nxt][(sq * 4 + 3) * 324 + p * 64 + sj] = xsr[p].w;
      }
#pragma unroll
      for (int q = 0; q < 10; ++q)
        Ws[nxt][wil * 324 + wjg + 32 * q] =
            fmaxf(fx * gar[q].x + fy * gar[q].y + fz * gar[q].z, 0.f);
    }
    __syncthreads();
  }

  // epilogue: reduce 16 jg-pages, apply 0.5*x + 0.5*R*sv, plain store
#pragma unroll
  for (int r = 0; r < 2; ++r)
#pragma unroll
    for (int kk = 0; kk < 4; ++kk)
      Red[jg * 136 + (rg * 2 + r) * 16 + (kg * 4 + kk)] = acc[r][kk];
  __syncthreads();
  if (t < 128) {
    const int il = t >> 4, kl = t & 15;
    float sv = 0.f;
#pragma unroll
    for (int g = 0; g < 16; ++g) sv += Red[g * 136 + il * 16 + kl];
    const int gi = i0 + il, gk = kbase + kl;
    Xout[(size_t)gi * 32 + gk] =
        0.5f * Xin[(size_t)gi * 32 + gk] + 0.5f * R[gi] * sv;
  }
}

// ---------------- phase: gram (5 blocks, j-partials; consumers sum) ---------
__global__ void __launch_bounds__(256)
k_gram(const float* __restrict__ Xa, const float* __restrict__ Xb,
       float* __restrict__ GPp) {
  __shared__ float sA[2048];
  __shared__ float sB[2048];
  const int bx = blockIdx.x, t = threadIdx.x;
  float acc[4] = {0.f, 0.f, 0.f, 0.f};
  for (int c = 0; c < 5; ++c) {
    const int j0 = bx * 320 + c * 64;
    __syncthreads();
    for (int s = t; s < 2048; s += 256) {
      sA[s] = Xa[(size_t)j0 * 32 + s];
      sB[s] = Xb[(size_t)j0 * 32 + s];
    }
    __syncthreads();
#pragma unroll
    for (int s = 0; s < 4; ++s) {
      int e = s * 256 + t;
      int a = e >> 5, b = e & 31;
      float sum = 0.f;
#pragma unroll 8
      for (int jl = 0; jl < 64; ++jl) sum += sA[jl * 32 + a] * sB[jl * 32 + b];
      acc[s] += sum;
    }
  }
#pragma unroll
  for (int s = 0; s < 4; ++s) GPp[(size_t)bx * 1024 + s * 256 + t] = acc[s];
}

// ---------------- phase: apply (200 blocks): chol + register trisolve -------
__global__ void __launch_bounds__(256)
k_apply(const float* __restrict__ GPp, const float* __restrict__ Xin,
        float* __restrict__ Xout) {
  __shared__ float Gm[32 * 33];
  const int bx = blockIdx.x, t = threadIdx.x;
#pragma unroll
  for (int u = 0; u < 4; ++u) {
    int e = t + u * 256;
    float g = 0.f;
#pragma unroll
    for (int p = 0; p < 5; ++p) g += GPp[p * 1024 + e];
    Gm[(e >> 5) * 33 + (e & 31)] = g;
  }
  const int r = t >> 5, l = t & 31;
  const int row = bx * 8 + r;
  float x = Xin[(size_t)row * M + l];
  __syncthreads();
  if (t < 64) {  // single-wave Cholesky, no barriers (wave-ordered LDS)
    for (int k = 0; k < 32; ++k) {
      if (t == k) Gm[k * 33 + k] = sqrtf(fmaxf(Gm[k * 33 + k], 1e-30f));
      float piv = Gm[k * 33 + k];
      if (t > k && t < 32) Gm[t * 33 + k] /= piv;
#pragma unroll
      for (int u = 0; u < 16; ++u) {
        int e = t + u * 64;
        int i = e >> 5, j = e & 31;
        if (i > k && j > k && j <= i)
          Gm[i * 33 + j] -= Gm[i * 33 + k] * Gm[j * 33 + k];
      }
    }
  }
  __syncthreads();
  const int half = t & 32;
  float y = 0.f;
  for (int k = 0; k < 32; ++k) {
    float gkl = Gm[k * 33 + l];
    float contrib = (l < k) ? y * gkl : 0.f;
#pragma unroll
    for (int o = 16; o; o >>= 1) contrib += __shfl_xor(contrib, o, 64);
    float xk = __shfl(x, half + k, 64);
    float yk = (xk - contrib) / Gm[k * 33 + k];
    if (l == k) y = yk;
  }
  Xout[(size_t)row * M + l] = y;
}

// ---------------- wave reductions (rr) --------------------------------------
__device__ __forceinline__ float wred(float v) {
#pragma unroll
  for (int o = 32; o; o >>= 1) v += __shfl_xor(v, o, 64);
  return v;
}

// ---------------- phase: rr (1 block x 1 wave, register-resident) -----------
// B is symmetric and the rank-2 Householder update preserves symmetry
// bit-exactly (v_i*u_j + u_i*v_j commutes), so lane i holds row i in
// registers and column k == row k. Full unroll makes all register indices
// static; v_c/u_c broadcast via __shfl — ZERO LDS in the loop. Round-7
// evidence: LDS round-trips + serial dot chain left 67us; this removes both
// (dot split into 4 chains).
__global__ void __launch_bounds__(64)
k_rr(const float* __restrict__ GPp, const int* __restrict__ flags,
     const int* __restrict__ Kptr, float* __restrict__ out) {
  __shared__ float Bs[1056];
  __shared__ float part[1024];
  __shared__ float evs[32];
  const int t = threadIdx.x;  // 0..63
#pragma unroll
  for (int u = 0; u < 16; ++u) {
    int e = t + u * 64;
    float g = 0.f;
#pragma unroll
    for (int p = 0; p < 5; ++p) g += GPp[p * 1024 + e];
    part[e] = g;
  }
  __syncthreads();
#pragma unroll
  for (int u = 0; u < 16; ++u) {
    int e = t + u * 64;
    int i = e >> 5, j = e & 31;
    Bs[i * 33 + j] = 0.5f * (part[e] + part[j * 32 + i]);
  }
  __syncthreads();
  const int tr = t & 31;
  float row[32];
#pragma unroll
  for (int c = 0; c < 32; ++c) row[c] = Bs[tr * 33 + c];
  float eer[32];
#pragma unroll
  for (int k = 0; k <= 29; ++k) {
    float xi = (t > k && t < 32) ? row[k] : 0.f;  // column k == row k (symm)
    float nx2 = wred(xi * xi);
    float x0 = __shfl(xi, k + 1, 64);
    if (nx2 < 1e-28f) { eer[k] = x0; continue; }
    float alpha = (x0 >= 0.f) ? -sqrtf(nx2) : sqrtf(nx2);
    float h = nx2 - alpha * x0;
    float vv = (t == k + 1) ? (xi - alpha) : xi;  // 0 outside active lanes
    eer[k] = alpha;
    float p0 = 0.f, p1 = 0.f, p2 = 0.f, p3 = 0.f;
#pragma unroll
    for (int c = 0; c < 32; c += 4) {
      p0 += row[c + 0] * __shfl(vv, c + 0, 64);
      p1 += row[c + 1] * __shfl(vv, c + 1, 64);
      p2 += row[c + 2] * __shfl(vv, c + 2, 64);
      p3 += row[c + 3] * __shfl(vv, c + 3, 64);
    }
    float pi = ((p0 + p1) + (p2 + p3)) / h;
    float vp = wred(vv * pi);  // vv==0 on inactive lanes -> exact 0 terms
    float Kc = vp / (2.f * h);
    float uu = (t > k && t < 32) ? (pi - Kc * vv) : 0.f;
#pragma unroll
    for (int c = 0; c < 32; ++c) {
      float uc = __shfl(uu, c, 64);
      float vc = __shfl(vv, c, 64);
      row[c] -= vv * uc + uu * vc;
    }
  }
  // extract tridiagonal (uniform across lanes via shfl; all static indices)
  float ddr[32];
#pragma unroll
  for (int c = 0; c < 32; ++c) ddr[c] = __shfl(row[c], c, 64);
  eer[30] = __shfl(row[30], 31, 64);
  eer[31] = 0.f;
  float ee2r[31];
#pragma unroll
  for (int c = 0; c < 31; ++c) ee2r[c] = eer[c] * eer[c];
  // Gershgorin bounds, scalar-unrolled (every lane has full dd/ee)
  float lo = 1e30f, hi = -1e30f;
#pragma unroll
  for (int i = 0; i < 32; ++i) {
    float r = ((i > 0) ? fabsf(eer[i - 1]) : 0.f) +
              ((i < 31) ? fabsf(eer[i]) : 0.f);
    lo = fminf(lo, ddr[i] - r);
    hi = fmaxf(hi, ddr[i] + r);
  }
  lo -= 1e-6f; hi += 1e-6f;
  if (t < 32) {
    float a = lo, b = hi;
    for (int it = 0; it < BIS_IT; ++it) {
      float mid = 0.5f * (a + b);
      float q = ddr[0] - mid;
      int cnt = (q < 0.f) ? 1 : 0;
#pragma unroll
      for (int i = 1; i < 32; ++i) {
        float den = q;
        float ad = fabsf(den);
        den = (ad < 1e-30f) ? ((den < 0.f) ? -1e-30f : 1e-30f) : den;
        q = ddr[i] - mid - ee2r[i - 1] * __builtin_amdgcn_rcpf(den);
        cnt += (q < 0.f) ? 1 : 0;
      }
      if (cnt <= t) a = mid; else b = mid;
    }
    evs[t] = 0.5f * (a + b);
  }
  __syncthreads();
  if (t == 0) {
    int K = Kptr ? *Kptr : 10;
    if (K < 1) K = 10;
    if (K > 32) K = 32;
    float t12 = 0.f, t13 = 0.f, t23 = 0.f;
    for (int b = 0; b < 8; ++b) {
      float f1 = flags[b * 2 + 0] ? 1.f : 0.f;
      float f2 = flags[b * 2 + 1] ? 1.f : 0.f;
      for (int k = 0; k < K; ++k) {
        float v1 = (k == 0) ? 0.f : (k == 1 ? f1 : 1.f);
        float v2 = (k == 0) ? 0.f : (k == 1 ? f2 : 1.f);
        float m3 = 2.f - 2.f * evs[31 - k];
        t12 += (v1 - v2) * (v1 - v2);
        t13 += (v1 - m3) * (v1 - m3);
        t23 += (v2 - m3) * (v2 - m3);
      }
    }
    out[0] = 5.f * (t12 + t13 + t23) / (8.f * (float)K);
  }
}

// ---------------- host: 30 sequential launches ------------------------------
extern "C" void kernel_launch(void* const* d_in, const int* in_sizes, int n_in,
                              void* d_out, int out_size, void* d_ws, size_t ws_size,
                              hipStream_t stream) {
  const float* feats = (const float*)d_in[0];
  const int* Kptr = (n_in > 1) ? (const int*)d_in[1] : nullptr;
  float* ws = (float*)d_ws;
  float* RZ = ws;                         // 38400
  float* F  = ws + 38400;                 // 4800
  float* G4f = ws + 43200;                // 6400 (1600 float4)
  float* R  = ws + 49600;                 // 1600
  int* FLAGS = (int*)(ws + 51200);        // 16 ints (64 reserved)
  float* GP = ws + 51264;                 // 3 x 5 x 1024 partials
  float* XB = ws + 51264 + 15360;         // 4 x XSZ ring
  float* bufs[4] = {XB, XB + XSZ, XB + 2 * XSZ, XB + 3 * XSZ};
  const float4* G4 = (const float4*)G4f;
  float* outp = (float*)d_out;

  k_resize<<<dim3(168), dim3(256), 0, stream>>>(feats, RZ);
  k_prep<<<dim3(23), dim3(256), 0, stream>>>(RZ, F, FLAGS);
  k_degree<<<dim3(100), dim3(256), 0, stream>>>(F, R, G4f, bufs[0]);

  const float* cur = bufs[0];
  for (int m = 1; m <= 10; ++m) {
    float* o = bufs[1 + m % 3];
    k_mv<<<dim3(400), dim3(256), 0, stream>>>(F, G4, R, cur, o);
    cur = o;
  }
  k_gram<<<dim3(5), dim3(256), 0, stream>>>(cur, cur, GP);
  k_apply<<<dim3(200), dim3(256), 0, stream>>>(GP, cur, bufs[0]);  // XV1
  cur = bufs[0];
  for (int m = 11; m <= 20; ++m) {
    float* o = bufs[1 + m % 3];
    k_mv<<<dim3(400), dim3(256), 0, stream>>>(F, G4, R, cur, o);
    cur = o;
  }
  k_gram<<<dim3(5), dim3(256), 0, stream>>>(cur, cur, GP + 5120);
  k_apply<<<dim3(200), dim3(256), 0, stream>>>(GP + 5120, cur, bufs[0]);  // XV2
  k_mv<<<dim3(400), dim3(256), 0, stream>>>(F, G4, R, bufs[0], bufs[1]);  // X21
  k_gram<<<dim3(5), dim3(256), 0, stream>>>(bufs[0], bufs[1], GP + 10240);
  k_rr<<<dim3(1), dim3(64), 0, stream>>>(GP + 10240, FLAGS, Kptr, outp);
}